// Round 6
// baseline (3346.029 us; speedup 1.0000x reference)
//
#include <hip/hip_runtime.h>

#define NPTS   32768
#define DIM    256
#define KCODES 8192

#define BM 128
#define BN 512
#define BK 16
#define NSPLIT 2
#define HSP (BM + 4)   // padded LDS pitch: 132f = 528B, 16B-aligned
#define CSP (BN + 4)   // 516f = 2064B, 16B-aligned

// ---------------- kernel 0: row squared-norms ----------------
__global__ __launch_bounds__(256) void norms_kernel(const float* __restrict__ src,
                                                    float* __restrict__ dst) {
  int row = blockIdx.x * 4 + (threadIdx.x >> 6);
  int lane = threadIdx.x & 63;
  float4 a = reinterpret_cast<const float4*>(src)[row * (DIM / 4) + lane];
  float sx = a.x * a.x, sy = a.y * a.y, sz = a.z * a.z, sw = a.w * a.w;
  double s = (double)sx + (double)sy + (double)sz + (double)sw;
#pragma unroll
  for (int m = 32; m; m >>= 1) s += __shfl_xor(s, m, 64);
  if (lane == 0) dst[row] = (float)s;
}

// ---------------- kernel 1: fused distance GEMM + argmin (code-split) --------
// waves_per_eu(2,2): pin the allocator's occupancy target to 2 waves/SIMD
// (= one 512-thread block/CU) so it allocates up to 256 VGPRs. r3/r5 showed
// the default targets 128 VGPRs (4 waves/SIMD) and spills dot[8][16]:
// ~1.8 GB scratch writes/dispatch, VALUBusy stuck at 30%.
__global__ __launch_bounds__(512)
__attribute__((amdgpu_waves_per_eu(2, 2))) void argmin_kernel(
    const float* __restrict__ h, const float* __restrict__ cb,
    const float* __restrict__ h2f, const float* __restrict__ c2f,
    float* __restrict__ bestval, int* __restrict__ bestidx) {
  __shared__ float hs[BK][HSP];   // 8.25 KB
  __shared__ float cs[BK][CSP];   // 32.25 KB
  const int t = threadIdx.x;
  const int ct = t & 31;
  const int pt = t >> 5;
  const int b = blockIdx.x;
  const int v = (b & 7) * 64 + (b >> 3);  // XCD-chunked bijective swizzle
  const int sblk = v >> 8;                // 0..1  (code slice)
  const int pblk = v & 255;               // 0..255 (point block)
  const int p0 = pblk * BM;
  const int cbase = sblk * (KCODES / NSPLIT);

  float best[8];
  int besti[8];
  float h2r[8];
#pragma unroll
  for (int i = 0; i < 8; ++i) {
    best[i] = 3.4e38f;
    besti[i] = 0;
    h2r[i] = h2f[p0 + pt * 4 + ((i >> 2) << 6) + (i & 3)];
  }

#pragma unroll 1
  for (int cc = 0; cc < KCODES / NSPLIT / BN; ++cc) {
    const int c0 = cbase + cc * BN;
    float dot[8][16];
#pragma unroll
    for (int i = 0; i < 8; ++i)
#pragma unroll
      for (int j = 0; j < 16; ++j) dot[i][j] = 0.f;

#pragma unroll 1
    for (int dd = 0; dd < DIM / BK; ++dd) {
      const int d0 = dd * BK;
      // stage h tile (transposed scatter): 512 float4, one per thread
      {
        int p = t >> 2, k4 = (t & 3) << 2;
        float4 w = *reinterpret_cast<const float4*>(h + (p0 + p) * DIM + d0 + k4);
        hs[k4 + 0][p] = w.x; hs[k4 + 1][p] = w.y;
        hs[k4 + 2][p] = w.z; hs[k4 + 3][p] = w.w;
      }
      // stage c tile: 2048 float4, four per thread
#pragma unroll
      for (int l = 0; l < 4; ++l) {
        int F = t + l * 512;
        int c = F >> 2, k4 = (F & 3) << 2;
        float4 w = *reinterpret_cast<const float4*>(cb + (c0 + c) * DIM + d0 + k4);
        cs[k4 + 0][c] = w.x; cs[k4 + 1][c] = w.y;
        cs[k4 + 2][c] = w.z; cs[k4 + 3][c] = w.w;
      }
      __syncthreads();
#pragma unroll
      for (int k = 0; k < BK; ++k) {
        float hv[8], cv[16];
        *reinterpret_cast<float4*>(&hv[0]) = *reinterpret_cast<const float4*>(&hs[k][pt * 4]);
        *reinterpret_cast<float4*>(&hv[4]) = *reinterpret_cast<const float4*>(&hs[k][pt * 4 + 64]);
        *reinterpret_cast<float4*>(&cv[0])  = *reinterpret_cast<const float4*>(&cs[k][ct * 4]);
        *reinterpret_cast<float4*>(&cv[4])  = *reinterpret_cast<const float4*>(&cs[k][ct * 4 + 128]);
        *reinterpret_cast<float4*>(&cv[8])  = *reinterpret_cast<const float4*>(&cs[k][ct * 4 + 256]);
        *reinterpret_cast<float4*>(&cv[12]) = *reinterpret_cast<const float4*>(&cs[k][ct * 4 + 384]);
#pragma unroll
        for (int i = 0; i < 8; ++i)
#pragma unroll
          for (int j = 0; j < 16; ++j)
            dot[i][j] = fmaf(hv[i], cv[j], dot[i][j]);
      }
      __syncthreads();
    }
    // numpy-fp32 scores + running argmin (ascending code order -> first-min)
#pragma unroll
    for (int j = 0; j < 16; ++j) {
      int cl = c0 + (ct << 2) + ((j >> 2) << 7) + (j & 3);
      float cc2 = c2f[cl];
#pragma unroll
      for (int i = 0; i < 8; ++i) {
        float A = h2r[i] + cc2;          // fl32(h2 + c2)
        float s = A - 2.0f * dot[i][j];  // fl32(A - 2*dot)
        if (s < best[i]) { best[i] = s; besti[i] = cl; }
      }
    }
  }
  // cross-lane reduce over the 32 ct-lanes (same pt), lowest-index tiebreak
#pragma unroll
  for (int i = 0; i < 8; ++i) {
    float b1 = best[i];
    int i1 = besti[i];
#pragma unroll
    for (int m = 16; m; m >>= 1) {
      float so = __shfl_xor(b1, m, 64);
      int io = __shfl_xor(i1, m, 64);
      if (so < b1 || (so == b1 && io < i1)) { b1 = so; i1 = io; }
    }
    if (ct == 0) {
      int p = p0 + pt * 4 + ((i >> 2) << 6) + (i & 3);
      bestval[sblk * NPTS + p] = b1;
      bestidx[sblk * NPTS + p] = i1;
    }
  }
}

// ---------------- kernel 1b: merge the two code-slices ----------------
__global__ __launch_bounds__(256) void merge_kernel(
    const float* __restrict__ bestval, const int* __restrict__ bestidx,
    int* __restrict__ idx, float* __restrict__ out_idx_f) {
  int p = blockIdx.x * 256 + threadIdx.x;
  float v0 = bestval[p], v1 = bestval[NPTS + p];
  int i0 = bestidx[p], i1 = bestidx[NPTS + p];
  // strict <: on fp32 ties slice0 (lower indices) wins == np.argmin semantics
  int w = (v1 < v0) ? i1 : i0;
  idx[p] = w;
  out_idx_f[p] = (float)w;
}

// ---------------- kernel 2: gather z, write z_q, masked sq-sum partials ------
__global__ __launch_bounds__(256) void gather_kernel(
    const float* __restrict__ h, const float* __restrict__ cb,
    const unsigned char* __restrict__ maskb, const int* __restrict__ idx,
    float* __restrict__ zq, float* __restrict__ partial) {
  int p = blockIdx.x * 4 + (threadIdx.x >> 6);
  int lane = threadIdx.x & 63;
  int ci = idx[p];
  float4 hv = reinterpret_cast<const float4*>(h)[p * (DIM / 4) + lane];
  float4 zv = reinterpret_cast<const float4*>(cb)[ci * (DIM / 4) + lane];
  float4 q;
  q.x = hv.x + (zv.x - hv.x);
  q.y = hv.y + (zv.y - hv.y);
  q.z = hv.z + (zv.z - hv.z);
  q.w = hv.w + (zv.w - hv.w);
  reinterpret_cast<float4*>(zq)[p * (DIM / 4) + lane] = q;
  float dx = hv.x - zv.x, dy = hv.y - zv.y, dz = hv.z - zv.z, dw = hv.w - zv.w;
  float s = (maskb[p] != 0) ? (dx * dx + dy * dy + dz * dz + dw * dw) : 0.f;
#pragma unroll
  for (int m = 32; m; m >>= 1) s += __shfl_xor(s, m, 64);
  __shared__ float bs[4];
  if (lane == 0) bs[threadIdx.x >> 6] = s;
  __syncthreads();
  if (threadIdx.x == 0) partial[blockIdx.x] = bs[0] + bs[1] + bs[2] + bs[3];
}

// ---------------- kernel 3: deterministic finalize ----------------
__global__ __launch_bounds__(256) void finalize_kernel(
    const float* __restrict__ partial, const unsigned char* __restrict__ maskb,
    float* __restrict__ out_losses) {
  __shared__ float red[256];
  __shared__ int redi[256];
  float s = 0.f;
  for (int i = threadIdx.x; i < NPTS / 4; i += 256) s += partial[i];
  int cnt = 0;
  for (int i = threadIdx.x; i < NPTS; i += 256) cnt += (maskb[i] != 0);
  red[threadIdx.x] = s;
  redi[threadIdx.x] = cnt;
  __syncthreads();
  for (int step = 128; step; step >>= 1) {
    if (threadIdx.x < step) {
      red[threadIdx.x] += red[threadIdx.x + step];
      redi[threadIdx.x] += redi[threadIdx.x + step];
    }
    __syncthreads();
  }
  if (threadIdx.x == 0) {
    float denom = (float)redi[0] * (float)DIM + 1e-8f;
    float loss = red[0] / denom;
    out_losses[0] = loss;   // commit_loss
    out_losses[1] = loss;   // codebook_loss (identical in forward)
  }
}

extern "C" void kernel_launch(void* const* d_in, const int* in_sizes, int n_in,
                              void* d_out, int out_size, void* d_ws, size_t ws_size,
                              hipStream_t stream) {
  const float* h = (const float*)d_in[0];
  const unsigned char* maskb = (const unsigned char*)d_in[1];
  const float* cb = (const float*)d_in[2];

  float* out = (float*)d_out;
  float* zq = out;                              // NPTS*DIM
  float* out_idx_f = out + NPTS * DIM;          // NPTS
  float* out_losses = out + NPTS * DIM + NPTS;  // 2

  char* ws = (char*)d_ws;
  float* h2f = (float*)(ws + 0);                 // 128KB [0,128K)
  float* c2f = (float*)(ws + (128 << 10));       // 32KB  [128K,160K)
  float* bestval = (float*)(ws + (160 << 10));   // 256KB [160K,416K)
  int* bestidx = (int*)(ws + (416 << 10));       // 256KB [416K,672K)
  int* idx = (int*)(ws + (672 << 10));           // 128KB [672K,800K)
  float* partial = (float*)(ws + (800 << 10));   // 32KB  [800K,832K)

  hipLaunchKernelGGL(norms_kernel, dim3(NPTS / 4), dim3(256), 0, stream, h, h2f);
  hipLaunchKernelGGL(norms_kernel, dim3(KCODES / 4), dim3(256), 0, stream, cb, c2f);
  hipLaunchKernelGGL(argmin_kernel, dim3(256 * NSPLIT), dim3(512), 0, stream,
                     h, cb, h2f, c2f, bestval, bestidx);
  hipLaunchKernelGGL(merge_kernel, dim3(NPTS / 256), dim3(256), 0, stream,
                     bestval, bestidx, idx, out_idx_f);
  hipLaunchKernelGGL(gather_kernel, dim3(NPTS / 4), dim3(256), 0, stream,
                     h, cb, maskb, idx, zq, partial);
  hipLaunchKernelGGL(finalize_kernel, dim3(1), dim3(256), 0, stream,
                     partial, maskb, out_losses);
}

// Round 7
// 1670.928 us; speedup vs baseline: 2.0025x; 2.0025x over previous
//
#include <hip/hip_runtime.h>

#define NPTS   32768
#define DIM    256
#define KCODES 8192

#define BM 128
#define BN 256
#define BK 16
#define NSPLIT 2
#define HSP (BM + 4)   // padded LDS pitch: 132f = 528B, 16B-aligned
#define CSP (BN + 4)   // 260f = 1040B, 16B-aligned

// ---------------- kernel 0: row squared-norms ----------------
__global__ __launch_bounds__(256) void norms_kernel(const float* __restrict__ src,
                                                    float* __restrict__ dst) {
  int row = blockIdx.x * 4 + (threadIdx.x >> 6);
  int lane = threadIdx.x & 63;
  float4 a = reinterpret_cast<const float4*>(src)[row * (DIM / 4) + lane];
  float sx = a.x * a.x, sy = a.y * a.y, sz = a.z * a.z, sw = a.w * a.w;
  double s = (double)sx + (double)sy + (double)sz + (double)sw;
#pragma unroll
  for (int m = 32; m; m >>= 1) s += __shfl_xor(s, m, 64);
  if (lane == 0) dst[row] = (float)s;
}

// ---------------- kernel 1: fused distance GEMM + argmin (code-split) --------
// 8x8 micro-tile (64 accumulators): total working set ~116 regs fits the
// 128-VGPR allocation with ZERO spill (r3-r6: 8x16 tile needed ~170 regs,
// allocator pinned 128 and spilled ~1.8 GB/dispatch to scratch; both
// waves_per_eu attempts failed to lift the cap). 128 VGPR = 4 waves/SIMD,
// so the 2 code-slice blocks per CU co-reside and hide each other's
// barrier/staging phases.
__global__ __launch_bounds__(512, 2) void argmin_kernel(
    const float* __restrict__ h, const float* __restrict__ cb,
    const float* __restrict__ h2f, const float* __restrict__ c2f,
    float* __restrict__ bestval, int* __restrict__ bestidx) {
  __shared__ float hs[BK][HSP];   // 8.25 KB
  __shared__ float cs[BK][CSP];   // 16.25 KB
  const int t = threadIdx.x;
  const int ct = t & 31;
  const int pt = t >> 5;
  const int b = blockIdx.x;
  const int v = (b & 7) * 64 + (b >> 3);  // XCD-chunked bijective swizzle
  const int sblk = v >> 8;                // 0..1  (code slice)
  const int pblk = v & 255;               // 0..255 (point block)
  const int p0 = pblk * BM;
  const int cbase = sblk * (KCODES / NSPLIT);

  float best[8];
  int besti[8];
  float h2r[8];
#pragma unroll
  for (int i = 0; i < 8; ++i) {
    best[i] = 3.4e38f;
    besti[i] = 0;
    h2r[i] = h2f[p0 + pt * 4 + ((i >> 2) << 6) + (i & 3)];
  }

#pragma unroll 1
  for (int cc = 0; cc < KCODES / NSPLIT / BN; ++cc) {
    const int c0 = cbase + cc * BN;
    float dot[8][8];
#pragma unroll
    for (int i = 0; i < 8; ++i)
#pragma unroll
      for (int j = 0; j < 8; ++j) dot[i][j] = 0.f;

#pragma unroll 1
    for (int dd = 0; dd < DIM / BK; ++dd) {
      const int d0 = dd * BK;
      // stage h tile (transposed scatter): 512 float4, one per thread
      {
        int p = t >> 2, k4 = (t & 3) << 2;
        float4 w = *reinterpret_cast<const float4*>(h + (p0 + p) * DIM + d0 + k4);
        hs[k4 + 0][p] = w.x; hs[k4 + 1][p] = w.y;
        hs[k4 + 2][p] = w.z; hs[k4 + 3][p] = w.w;
      }
      // stage c tile: 1024 float4, two per thread
#pragma unroll
      for (int l = 0; l < 2; ++l) {
        int F = t + l * 512;
        int c = F >> 2, k4 = (F & 3) << 2;
        float4 w = *reinterpret_cast<const float4*>(cb + (c0 + c) * DIM + d0 + k4);
        cs[k4 + 0][c] = w.x; cs[k4 + 1][c] = w.y;
        cs[k4 + 2][c] = w.z; cs[k4 + 3][c] = w.w;
      }
      __syncthreads();
#pragma unroll
      for (int k = 0; k < BK; ++k) {
        float hv[8], cv[8];
        *reinterpret_cast<float4*>(&hv[0]) = *reinterpret_cast<const float4*>(&hs[k][pt * 4]);
        *reinterpret_cast<float4*>(&hv[4]) = *reinterpret_cast<const float4*>(&hs[k][pt * 4 + 64]);
        *reinterpret_cast<float4*>(&cv[0]) = *reinterpret_cast<const float4*>(&cs[k][ct * 4]);
        *reinterpret_cast<float4*>(&cv[4]) = *reinterpret_cast<const float4*>(&cs[k][ct * 4 + 128]);
#pragma unroll
        for (int i = 0; i < 8; ++i)
#pragma unroll
          for (int j = 0; j < 8; ++j)
            dot[i][j] = fmaf(hv[i], cv[j], dot[i][j]);
      }
      __syncthreads();
    }
    // numpy-fp32 scores + running argmin (ascending code order -> first-min)
#pragma unroll
    for (int j = 0; j < 8; ++j) {
      int cl = c0 + (ct << 2) + ((j >> 2) << 7) + (j & 3);
      float cc2 = c2f[cl];
#pragma unroll
      for (int i = 0; i < 8; ++i) {
        float A = h2r[i] + cc2;          // fl32(h2 + c2)
        float s = A - 2.0f * dot[i][j];  // fl32(A - 2*dot)
        if (s < best[i]) { best[i] = s; besti[i] = cl; }
      }
    }
  }
  // cross-lane reduce over the 32 ct-lanes (same pt), lowest-index tiebreak
#pragma unroll
  for (int i = 0; i < 8; ++i) {
    float b1 = best[i];
    int i1 = besti[i];
#pragma unroll
    for (int m = 16; m; m >>= 1) {
      float so = __shfl_xor(b1, m, 64);
      int io = __shfl_xor(i1, m, 64);
      if (so < b1 || (so == b1 && io < i1)) { b1 = so; i1 = io; }
    }
    if (ct == 0) {
      int p = p0 + pt * 4 + ((i >> 2) << 6) + (i & 3);
      bestval[sblk * NPTS + p] = b1;
      bestidx[sblk * NPTS + p] = i1;
    }
  }
}

// ---------------- kernel 1b: merge the two code-slices ----------------
__global__ __launch_bounds__(256) void merge_kernel(
    const float* __restrict__ bestval, const int* __restrict__ bestidx,
    int* __restrict__ idx, float* __restrict__ out_idx_f) {
  int p = blockIdx.x * 256 + threadIdx.x;
  float v0 = bestval[p], v1 = bestval[NPTS + p];
  int i0 = bestidx[p], i1 = bestidx[NPTS + p];
  // strict <: on fp32 ties slice0 (lower indices) wins == np.argmin semantics
  int w = (v1 < v0) ? i1 : i0;
  idx[p] = w;
  out_idx_f[p] = (float)w;
}

// ---------------- kernel 2: gather z, write z_q, masked sq-sum partials ------
__global__ __launch_bounds__(256) void gather_kernel(
    const float* __restrict__ h, const float* __restrict__ cb,
    const unsigned char* __restrict__ maskb, const int* __restrict__ idx,
    float* __restrict__ zq, float* __restrict__ partial) {
  int p = blockIdx.x * 4 + (threadIdx.x >> 6);
  int lane = threadIdx.x & 63;
  int ci = idx[p];
  float4 hv = reinterpret_cast<const float4*>(h)[p * (DIM / 4) + lane];
  float4 zv = reinterpret_cast<const float4*>(cb)[ci * (DIM / 4) + lane];
  float4 q;
  q.x = hv.x + (zv.x - hv.x);
  q.y = hv.y + (zv.y - hv.y);
  q.z = hv.z + (zv.z - hv.z);
  q.w = hv.w + (zv.w - hv.w);
  reinterpret_cast<float4*>(zq)[p * (DIM / 4) + lane] = q;
  float dx = hv.x - zv.x, dy = hv.y - zv.y, dz = hv.z - zv.z, dw = hv.w - zv.w;
  float s = (maskb[p] != 0) ? (dx * dx + dy * dy + dz * dz + dw * dw) : 0.f;
#pragma unroll
  for (int m = 32; m; m >>= 1) s += __shfl_xor(s, m, 64);
  __shared__ float bs[4];
  if (lane == 0) bs[threadIdx.x >> 6] = s;
  __syncthreads();
  if (threadIdx.x == 0) partial[blockIdx.x] = bs[0] + bs[1] + bs[2] + bs[3];
}

// ---------------- kernel 3: deterministic finalize ----------------
__global__ __launch_bounds__(256) void finalize_kernel(
    const float* __restrict__ partial, const unsigned char* __restrict__ maskb,
    float* __restrict__ out_losses) {
  __shared__ float red[256];
  __shared__ int redi[256];
  float s = 0.f;
  for (int i = threadIdx.x; i < NPTS / 4; i += 256) s += partial[i];
  int cnt = 0;
  for (int i = threadIdx.x; i < NPTS; i += 256) cnt += (maskb[i] != 0);
  red[threadIdx.x] = s;
  redi[threadIdx.x] = cnt;
  __syncthreads();
  for (int step = 128; step; step >>= 1) {
    if (threadIdx.x < step) {
      red[threadIdx.x] += red[threadIdx.x + step];
      redi[threadIdx.x] += redi[threadIdx.x + step];
    }
    __syncthreads();
  }
  if (threadIdx.x == 0) {
    float denom = (float)redi[0] * (float)DIM + 1e-8f;
    float loss = red[0] / denom;
    out_losses[0] = loss;   // commit_loss
    out_losses[1] = loss;   // codebook_loss (identical in forward)
  }
}

extern "C" void kernel_launch(void* const* d_in, const int* in_sizes, int n_in,
                              void* d_out, int out_size, void* d_ws, size_t ws_size,
                              hipStream_t stream) {
  const float* h = (const float*)d_in[0];
  const unsigned char* maskb = (const unsigned char*)d_in[1];
  const float* cb = (const float*)d_in[2];

  float* out = (float*)d_out;
  float* zq = out;                              // NPTS*DIM
  float* out_idx_f = out + NPTS * DIM;          // NPTS
  float* out_losses = out + NPTS * DIM + NPTS;  // 2

  char* ws = (char*)d_ws;
  float* h2f = (float*)(ws + 0);                 // 128KB [0,128K)
  float* c2f = (float*)(ws + (128 << 10));       // 32KB  [128K,160K)
  float* bestval = (float*)(ws + (160 << 10));   // 256KB [160K,416K)
  int* bestidx = (int*)(ws + (416 << 10));       // 256KB [416K,672K)
  int* idx = (int*)(ws + (672 << 10));           // 128KB [672K,800K)
  float* partial = (float*)(ws + (800 << 10));   // 32KB  [800K,832K)

  hipLaunchKernelGGL(norms_kernel, dim3(NPTS / 4), dim3(256), 0, stream, h, h2f);
  hipLaunchKernelGGL(norms_kernel, dim3(KCODES / 4), dim3(256), 0, stream, cb, c2f);
  hipLaunchKernelGGL(argmin_kernel, dim3(256 * NSPLIT), dim3(512), 0, stream,
                     h, cb, h2f, c2f, bestval, bestidx);
  hipLaunchKernelGGL(merge_kernel, dim3(NPTS / 256), dim3(256), 0, stream,
                     bestval, bestidx, idx, out_idx_f);
  hipLaunchKernelGGL(gather_kernel, dim3(NPTS / 4), dim3(256), 0, stream,
                     h, cb, maskb, idx, zq, partial);
  hipLaunchKernelGGL(finalize_kernel, dim3(1), dim3(256), 0, stream,
                     partial, maskb, out_losses);
}

// Round 8
// 883.012 us; speedup vs baseline: 3.7893x; 1.8923x over previous
//
#include <hip/hip_runtime.h>

#define NPTS   32768
#define DIM    256
#define KCODES 8192
#define TAU    2e-4f

typedef __attribute__((ext_vector_type(8))) short bf16x8;
typedef __attribute__((ext_vector_type(4))) float f32x4;

__device__ __forceinline__ unsigned short f2bf(float x) {  // RNE bf16
  unsigned u = __float_as_uint(x);
  unsigned r = (u + 0x7fffu + ((u >> 16) & 1u)) >> 16;
  return (unsigned short)r;
}
__device__ __forceinline__ float bf2f(unsigned short b) {
  return __uint_as_float(((unsigned)b) << 16);
}

// ---------------- row squared-norms (fl32 of f64-accurate sum) ----------------
__global__ __launch_bounds__(256) void norms_kernel(const float* __restrict__ src,
                                                    float* __restrict__ dst) {
  int row = blockIdx.x * 4 + (threadIdx.x >> 6);
  int lane = threadIdx.x & 63;
  float4 a = reinterpret_cast<const float4*>(src)[row * (DIM / 4) + lane];
  float sx = a.x * a.x, sy = a.y * a.y, sz = a.z * a.z, sw = a.w * a.w;
  double s = (double)sx + (double)sy + (double)sz + (double)sw;
#pragma unroll
  for (int m = 32; m; m >>= 1) s += __shfl_xor(s, m, 64);
  if (lane == 0) dst[row] = (float)s;
}

// ---------------- bf16 hi/lo split ----------------
__global__ __launch_bounds__(256) void split_kernel(const float* __restrict__ src,
                                                    unsigned short* __restrict__ hi,
                                                    unsigned short* __restrict__ lo,
                                                    int n4) {
  int i = blockIdx.x * 256 + threadIdx.x;
  int stride = gridDim.x * 256;
  for (; i < n4; i += stride) {
    float4 v = reinterpret_cast<const float4*>(src)[i];
    ushort4 h, l;
    h.x = f2bf(v.x); l.x = f2bf(v.x - bf2f(h.x));
    h.y = f2bf(v.y); l.y = f2bf(v.y - bf2f(h.y));
    h.z = f2bf(v.z); l.z = f2bf(v.z - bf2f(h.z));
    h.w = f2bf(v.w); l.w = f2bf(v.w - bf2f(h.w));
    reinterpret_cast<ushort4*>(hi)[i] = h;
    reinterpret_cast<ushort4*>(lo)[i] = l;
  }
}

__global__ void zero_kernel(int* __restrict__ flagcnt) { *flagcnt = 0; }

// ---------------- MFMA distance GEMM + per-point top-2 ----------------
// 8 waves = 4 point-rows x 2 code-cols; wave tile 32pt x 64codes of 16x16x32
// subtiles; 3-pass bf16 split accumulating one fp32 acc. Score form identical
// to the passing fp32 kernel: s = fmaf(-2, dot, fl(h2f+c2f)). Grid 512 =
// 256 point-blocks x NSPLIT(2) code slices, XCD-chunked. LDS tiles [row][32]
// bf16 (64B rows) with 16B-block XOR swizzle (blk ^= (row>>1)&3).
__global__ __launch_bounds__(512, 2) void mfma_argmin_kernel(
    const unsigned short* __restrict__ hh, const unsigned short* __restrict__ hl,
    const unsigned short* __restrict__ ch, const unsigned short* __restrict__ cl,
    const float* __restrict__ h2f, const float* __restrict__ c2f,
    float* __restrict__ bv, int* __restrict__ bi, float* __restrict__ b2o) {
  __shared__ __align__(16) unsigned short As0[4096], As1[4096], Bs0[4096], Bs1[4096];
  const int t = threadIdx.x;
  const int lane = t & 63;
  const int wid = t >> 6;
  const int wrow = wid >> 1, wcol = wid & 1;
  const int b = blockIdx.x;
  const int v = (b & 7) * 64 + (b >> 3);   // XCD-chunked bijective swizzle
  const int sblk = v >> 8, pblk = v & 255;
  const int p0 = pblk * 128;
  const int cbase = sblk * (KCODES / 2);

  // staging: thread t owns one 16B block per tile
  const int strow = t >> 2, stblk = t & 3;
  const int stoff = strow * 64 + ((stblk ^ ((strow >> 1) & 3)) << 4);
  const uint4* hh4 = (const uint4*)hh;
  const uint4* hl4 = (const uint4*)hl;
  const uint4* ch4 = (const uint4*)ch;
  const uint4* cl4 = (const uint4*)cl;
  const int arow4 = (p0 + strow) * 32 + stblk;

  // fragment read offsets (A rows: wrow*32 + sr*16 + (lane&15); k-blk = lane>>4)
  const int ablk = lane >> 4;
  const int ar0 = wrow * 32 + (lane & 15);
  const int ar1 = ar0 + 16;
  const int aoff0 = ar0 * 64 + ((ablk ^ ((ar0 >> 1) & 3)) << 4);
  const int aoff1 = ar1 * 64 + ((ablk ^ ((ar1 >> 1) & 3)) << 4);
  int boff[4];
#pragma unroll
  for (int sc = 0; sc < 4; ++sc) {
    int cr = wcol * 64 + sc * 16 + (lane & 15);
    boff[sc] = cr * 64 + ((ablk ^ ((cr >> 1) & 3)) << 4);
  }

  float h2r[8];
#pragma unroll
  for (int sr = 0; sr < 2; ++sr)
#pragma unroll
    for (int r = 0; r < 4; ++r)
      h2r[sr * 4 + r] = h2f[p0 + wrow * 32 + sr * 16 + ((lane >> 4) << 2) + r];

  float sb1[8], sbt2[8];
  int si1[8];
#pragma unroll
  for (int s = 0; s < 8; ++s) { sb1[s] = 3.4e38f; sbt2[s] = 3.4e38f; si1[s] = 0; }

#pragma unroll 1
  for (int cc = 0; cc < (KCODES / 2) / 128; ++cc) {
    f32x4 acc[8];
#pragma unroll
    for (int s = 0; s < 8; ++s) acc[s] = (f32x4){0.f, 0.f, 0.f, 0.f};
    const int brow4 = (cbase + cc * 128 + strow) * 32 + stblk;

#pragma unroll 1
    for (int dd = 0; dd < 8; ++dd) {
      uint4 va0 = hh4[arow4 + dd * 4];
      uint4 va1 = hl4[arow4 + dd * 4];
      uint4 vb0 = ch4[brow4 + dd * 4];
      uint4 vb1 = cl4[brow4 + dd * 4];
      __syncthreads();
      *(uint4*)((char*)As0 + stoff) = va0;
      *(uint4*)((char*)As1 + stoff) = va1;
      *(uint4*)((char*)Bs0 + stoff) = vb0;
      *(uint4*)((char*)Bs1 + stoff) = vb1;
      __syncthreads();
      bf16x8 a0h = *(const bf16x8*)((const char*)As0 + aoff0);
      bf16x8 a0l = *(const bf16x8*)((const char*)As1 + aoff0);
      bf16x8 a1h = *(const bf16x8*)((const char*)As0 + aoff1);
      bf16x8 a1l = *(const bf16x8*)((const char*)As1 + aoff1);
#pragma unroll
      for (int sc = 0; sc < 4; ++sc) {
        bf16x8 bh = *(const bf16x8*)((const char*)Bs0 + boff[sc]);
        bf16x8 bl = *(const bf16x8*)((const char*)Bs1 + boff[sc]);
        acc[sc] = __builtin_amdgcn_mfma_f32_16x16x32_bf16(a0h, bh, acc[sc], 0, 0, 0);
        acc[sc] = __builtin_amdgcn_mfma_f32_16x16x32_bf16(a0l, bh, acc[sc], 0, 0, 0);
        acc[sc] = __builtin_amdgcn_mfma_f32_16x16x32_bf16(a0h, bl, acc[sc], 0, 0, 0);
        acc[4 + sc] = __builtin_amdgcn_mfma_f32_16x16x32_bf16(a1h, bh, acc[4 + sc], 0, 0, 0);
        acc[4 + sc] = __builtin_amdgcn_mfma_f32_16x16x32_bf16(a1l, bh, acc[4 + sc], 0, 0, 0);
        acc[4 + sc] = __builtin_amdgcn_mfma_f32_16x16x32_bf16(a1h, bl, acc[4 + sc], 0, 0, 0);
      }
    }
    // epilogue: scores + per-slot running top-2 (ascending code order)
#pragma unroll
    for (int sc = 0; sc < 4; ++sc) {
      int col = cbase + cc * 128 + wcol * 64 + sc * 16 + (lane & 15);
      float c2v = c2f[col];
#pragma unroll
      for (int sr = 0; sr < 2; ++sr)
#pragma unroll
        for (int r = 0; r < 4; ++r) {
          int slot = sr * 4 + r;
          float A = h2r[slot] + c2v;
          float s = fmaf(-2.f, acc[sr * 4 + sc][r], A);
          if (s < sb1[slot]) { sbt2[slot] = sb1[slot]; sb1[slot] = s; si1[slot] = col; }
          else if (s < sbt2[slot]) sbt2[slot] = s;
        }
    }
  }
  // cross-lane top-2 merge over the 16 col-lanes (lowest-index tiebreak on b1)
#pragma unroll
  for (int slot = 0; slot < 8; ++slot) {
    float b1 = sb1[slot]; int i1 = si1[slot]; float b2 = sbt2[slot];
#pragma unroll
    for (int m = 1; m <= 8; m <<= 1) {
      float ob1 = __shfl_xor(b1, m, 64);
      int oi1 = __shfl_xor(i1, m, 64);
      float ob2 = __shfl_xor(b2, m, 64);
      float loser = fmaxf(b1, ob1);
      float nb2 = fminf(fminf(b2, ob2), loser);
      if (ob1 < b1 || (ob1 == b1 && oi1 < i1)) { b1 = ob1; i1 = oi1; }
      b2 = nb2;
    }
    if ((lane & 15) == 0) {
      int p = p0 + wrow * 32 + (slot >> 2) * 16 + ((lane >> 4) << 2) + (slot & 3);
      int part = sblk * 2 + wcol;
      bv[part * NPTS + p] = b1;
      bi[part * NPTS + p] = i1;
      b2o[part * NPTS + p] = b2;
    }
  }
}

// ---------------- merge 4 partials + flag near-ties ----------------
__global__ __launch_bounds__(256) void merge_flag_kernel(
    const float* __restrict__ bv, const int* __restrict__ bi,
    const float* __restrict__ b2o, int* __restrict__ idx,
    float* __restrict__ out_idx_f, int* __restrict__ flagcnt,
    int* __restrict__ flaglist) {
  int p = blockIdx.x * 256 + threadIdx.x;
  float b1 = bv[p]; int i1 = bi[p]; float b2 = b2o[p];
#pragma unroll
  for (int part = 1; part < 4; ++part) {
    float pb1 = bv[part * NPTS + p];
    int pi1 = bi[part * NPTS + p];
    float pb2 = b2o[part * NPTS + p];
    float loser = fmaxf(b1, pb1);
    float nb2 = fminf(fminf(b2, pb2), loser);
    if (pb1 < b1 || (pb1 == b1 && pi1 < i1)) { b1 = pb1; i1 = pi1; }
    b2 = nb2;
  }
  idx[p] = i1;
  out_idx_f[p] = (float)i1;
  if (b2 - b1 < TAU) { int s = atomicAdd(flagcnt, 1); flaglist[s] = p; }
}

// ---------------- exact numpy-semantics re-argmin for flagged points ----------
__global__ __launch_bounds__(256) void refine_kernel(
    const float* __restrict__ h, const float* __restrict__ cb,
    const float* __restrict__ h2f, const float* __restrict__ c2f,
    const int* __restrict__ flagcnt, const int* __restrict__ flaglist,
    int* __restrict__ idx, float* __restrict__ out_idx_f) {
  __shared__ float hrow[DIM];
  __shared__ float rb[256];
  __shared__ int ri[256];
  const int n = *flagcnt;
  for (int e = blockIdx.x; e < n; e += gridDim.x) {
    const int p = flaglist[e];
    __syncthreads();
    if (threadIdx.x < DIM / 4)
      reinterpret_cast<float4*>(hrow)[threadIdx.x] =
          reinterpret_cast<const float4*>(h + p * DIM)[threadIdx.x];
    __syncthreads();
    const float h2 = h2f[p];
    float b1 = 3.4e38f;
    int i1 = 0x7fffffff;
    for (int c = threadIdx.x; c < KCODES; c += 256) {
      const float4* crow = reinterpret_cast<const float4*>(cb + c * DIM);
      float dot = 0.f;
#pragma unroll 16
      for (int d4 = 0; d4 < DIM / 4; ++d4) {
        float4 cv = crow[d4];
        dot = fmaf(hrow[4 * d4 + 0], cv.x, dot);
        dot = fmaf(hrow[4 * d4 + 1], cv.y, dot);
        dot = fmaf(hrow[4 * d4 + 2], cv.z, dot);
        dot = fmaf(hrow[4 * d4 + 3], cv.w, dot);
      }
      float A = h2 + c2f[c];
      float s = fmaf(-2.f, dot, A);
      if (s < b1) { b1 = s; i1 = c; }
    }
    rb[threadIdx.x] = b1;
    ri[threadIdx.x] = i1;
    __syncthreads();
    for (int step = 128; step; step >>= 1) {
      if (threadIdx.x < step) {
        float ob = rb[threadIdx.x + step];
        int oi = ri[threadIdx.x + step];
        if (ob < rb[threadIdx.x] || (ob == rb[threadIdx.x] && oi < ri[threadIdx.x])) {
          rb[threadIdx.x] = ob;
          ri[threadIdx.x] = oi;
        }
      }
      __syncthreads();
    }
    if (threadIdx.x == 0) { idx[p] = ri[0]; out_idx_f[p] = (float)ri[0]; }
  }
}

// ---------------- fallback: r7 fp32 argmin (8x8 tile) + 2-way merge ----------
__global__ __launch_bounds__(512, 2) void argmin_fp32_kernel(
    const float* __restrict__ h, const float* __restrict__ cb,
    const float* __restrict__ h2f, const float* __restrict__ c2f,
    float* __restrict__ bestval, int* __restrict__ bestidx) {
  __shared__ float hs[16][132];
  __shared__ float cs[16][260];
  const int t = threadIdx.x;
  const int ct = t & 31;
  const int pt = t >> 5;
  const int b = blockIdx.x;
  const int v = (b & 7) * 64 + (b >> 3);
  const int sblk = v >> 8;
  const int pblk = v & 255;
  const int p0 = pblk * 128;
  const int cbase = sblk * (KCODES / 2);
  float best[8]; int besti[8]; float h2r[8];
#pragma unroll
  for (int i = 0; i < 8; ++i) {
    best[i] = 3.4e38f; besti[i] = 0;
    h2r[i] = h2f[p0 + pt * 4 + ((i >> 2) << 6) + (i & 3)];
  }
#pragma unroll 1
  for (int cc = 0; cc < (KCODES / 2) / 256; ++cc) {
    const int c0 = cbase + cc * 256;
    float dot[8][8];
#pragma unroll
    for (int i = 0; i < 8; ++i)
#pragma unroll
      for (int j = 0; j < 8; ++j) dot[i][j] = 0.f;
#pragma unroll 1
    for (int dd = 0; dd < DIM / 16; ++dd) {
      const int d0 = dd * 16;
      {
        int p = t >> 2, k4 = (t & 3) << 2;
        float4 w = *reinterpret_cast<const float4*>(h + (p0 + p) * DIM + d0 + k4);
        hs[k4 + 0][p] = w.x; hs[k4 + 1][p] = w.y;
        hs[k4 + 2][p] = w.z; hs[k4 + 3][p] = w.w;
      }
#pragma unroll
      for (int l = 0; l < 2; ++l) {
        int F = t + l * 512;
        int c = F >> 2, k4 = (F & 3) << 2;
        float4 w = *reinterpret_cast<const float4*>(cb + (c0 + c) * DIM + d0 + k4);
        cs[k4 + 0][c] = w.x; cs[k4 + 1][c] = w.y;
        cs[k4 + 2][c] = w.z; cs[k4 + 3][c] = w.w;
      }
      __syncthreads();
#pragma unroll
      for (int k = 0; k < 16; ++k) {
        float hv[8], cv[8];
        *reinterpret_cast<float4*>(&hv[0]) = *reinterpret_cast<const float4*>(&hs[k][pt * 4]);
        *reinterpret_cast<float4*>(&hv[4]) = *reinterpret_cast<const float4*>(&hs[k][pt * 4 + 64]);
        *reinterpret_cast<float4*>(&cv[0]) = *reinterpret_cast<const float4*>(&cs[k][ct * 4]);
        *reinterpret_cast<float4*>(&cv[4]) = *reinterpret_cast<const float4*>(&cs[k][ct * 4 + 128]);
#pragma unroll
        for (int i = 0; i < 8; ++i)
#pragma unroll
          for (int j = 0; j < 8; ++j) dot[i][j] = fmaf(hv[i], cv[j], dot[i][j]);
      }
      __syncthreads();
    }
#pragma unroll
    for (int j = 0; j < 8; ++j) {
      int cl = c0 + (ct << 2) + ((j >> 2) << 7) + (j & 3);
      float cc2 = c2f[cl];
#pragma unroll
      for (int i = 0; i < 8; ++i) {
        float A = h2r[i] + cc2;
        float s = A - 2.0f * dot[i][j];
        if (s < best[i]) { best[i] = s; besti[i] = cl; }
      }
    }
  }
#pragma unroll
  for (int i = 0; i < 8; ++i) {
    float b1 = best[i]; int i1 = besti[i];
#pragma unroll
    for (int m = 16; m; m >>= 1) {
      float so = __shfl_xor(b1, m, 64);
      int io = __shfl_xor(i1, m, 64);
      if (so < b1 || (so == b1 && io < i1)) { b1 = so; i1 = io; }
    }
    if (ct == 0) {
      int p = p0 + pt * 4 + ((i >> 2) << 6) + (i & 3);
      bestval[sblk * NPTS + p] = b1;
      bestidx[sblk * NPTS + p] = i1;
    }
  }
}

__global__ __launch_bounds__(256) void merge2_kernel(
    const float* __restrict__ bestval, const int* __restrict__ bestidx,
    int* __restrict__ idx, float* __restrict__ out_idx_f) {
  int p = blockIdx.x * 256 + threadIdx.x;
  float v0 = bestval[p], v1 = bestval[NPTS + p];
  int i0 = bestidx[p], i1 = bestidx[NPTS + p];
  int w = (v1 < v0) ? i1 : i0;
  idx[p] = w;
  out_idx_f[p] = (float)w;
}

// ---------------- gather + finalize ----------------
__global__ __launch_bounds__(256) void gather_kernel(
    const float* __restrict__ h, const float* __restrict__ cb,
    const unsigned char* __restrict__ maskb, const int* __restrict__ idx,
    float* __restrict__ zq, float* __restrict__ partial) {
  int p = blockIdx.x * 4 + (threadIdx.x >> 6);
  int lane = threadIdx.x & 63;
  int ci = idx[p];
  float4 hv = reinterpret_cast<const float4*>(h)[p * (DIM / 4) + lane];
  float4 zv = reinterpret_cast<const float4*>(cb)[ci * (DIM / 4) + lane];
  float4 q;
  q.x = hv.x + (zv.x - hv.x);
  q.y = hv.y + (zv.y - hv.y);
  q.z = hv.z + (zv.z - hv.z);
  q.w = hv.w + (zv.w - hv.w);
  reinterpret_cast<float4*>(zq)[p * (DIM / 4) + lane] = q;
  float dx = hv.x - zv.x, dy = hv.y - zv.y, dz = hv.z - zv.z, dw = hv.w - zv.w;
  float s = (maskb[p] != 0) ? (dx * dx + dy * dy + dz * dz + dw * dw) : 0.f;
#pragma unroll
  for (int m = 32; m; m >>= 1) s += __shfl_xor(s, m, 64);
  __shared__ float bs[4];
  if (lane == 0) bs[threadIdx.x >> 6] = s;
  __syncthreads();
  if (threadIdx.x == 0) partial[blockIdx.x] = bs[0] + bs[1] + bs[2] + bs[3];
}

__global__ __launch_bounds__(256) void finalize_kernel(
    const float* __restrict__ partial, const unsigned char* __restrict__ maskb,
    float* __restrict__ out_losses) {
  __shared__ float red[256];
  __shared__ int redi[256];
  float s = 0.f;
  for (int i = threadIdx.x; i < NPTS / 4; i += 256) s += partial[i];
  int cnt = 0;
  for (int i = threadIdx.x; i < NPTS; i += 256) cnt += (maskb[i] != 0);
  red[threadIdx.x] = s;
  redi[threadIdx.x] = cnt;
  __syncthreads();
  for (int step = 128; step; step >>= 1) {
    if (threadIdx.x < step) {
      red[threadIdx.x] += red[threadIdx.x + step];
      redi[threadIdx.x] += redi[threadIdx.x + step];
    }
    __syncthreads();
  }
  if (threadIdx.x == 0) {
    float denom = (float)redi[0] * (float)DIM + 1e-8f;
    float loss = red[0] / denom;
    out_losses[0] = loss;
    out_losses[1] = loss;
  }
}

extern "C" void kernel_launch(void* const* d_in, const int* in_sizes, int n_in,
                              void* d_out, int out_size, void* d_ws, size_t ws_size,
                              hipStream_t stream) {
  const float* h = (const float*)d_in[0];
  const unsigned char* maskb = (const unsigned char*)d_in[1];
  const float* cb = (const float*)d_in[2];

  float* out = (float*)d_out;
  float* zq = out;
  float* out_idx_f = out + NPTS * DIM;
  float* out_losses = out + NPTS * DIM + NPTS;

  char* ws = (char*)d_ws;
  const size_t REQ = 44040192ULL;  // 42 MB

  if (ws_size >= REQ) {
    float* h2f = (float*)(ws + 0);                    // 128K
    float* c2f = (float*)(ws + 131072);               // 32K
    float* bv = (float*)(ws + 163840);                // 512K
    int* bi = (int*)(ws + 688128);                    // 512K
    float* b2o = (float*)(ws + 1212416);              // 512K
    int* idx = (int*)(ws + 1736704);                  // 128K
    float* partial = (float*)(ws + 1867776);          // 32K
    int* flagcnt = (int*)(ws + 1900544);              // 4 (+pad)
    int* flaglist = (int*)(ws + 1904640);             // 128K
    unsigned short* hh = (unsigned short*)(ws + 2097152);    // 16M
    unsigned short* hl = (unsigned short*)(ws + 18874368);   // 16M
    unsigned short* chh = (unsigned short*)(ws + 35651584);  // 4M
    unsigned short* cll = (unsigned short*)(ws + 39845888);  // 4M

    hipLaunchKernelGGL(norms_kernel, dim3(NPTS / 4), dim3(256), 0, stream, h, h2f);
    hipLaunchKernelGGL(norms_kernel, dim3(KCODES / 4), dim3(256), 0, stream, cb, c2f);
    hipLaunchKernelGGL(split_kernel, dim3(2048), dim3(256), 0, stream,
                       h, hh, hl, NPTS * DIM / 4);
    hipLaunchKernelGGL(split_kernel, dim3(2048), dim3(256), 0, stream,
                       cb, chh, cll, KCODES * DIM / 4);
    hipLaunchKernelGGL(zero_kernel, dim3(1), dim3(1), 0, stream, flagcnt);
    hipLaunchKernelGGL(mfma_argmin_kernel, dim3(512), dim3(512), 0, stream,
                       hh, hl, chh, cll, h2f, c2f, bv, bi, b2o);
    hipLaunchKernelGGL(merge_flag_kernel, dim3(NPTS / 256), dim3(256), 0, stream,
                       bv, bi, b2o, idx, out_idx_f, flagcnt, flaglist);
    hipLaunchKernelGGL(refine_kernel, dim3(512), dim3(256), 0, stream,
                       h, cb, h2f, c2f, flagcnt, flaglist, idx, out_idx_f);
    hipLaunchKernelGGL(gather_kernel, dim3(NPTS / 4), dim3(256), 0, stream,
                       h, cb, maskb, idx, zq, partial);
    hipLaunchKernelGGL(finalize_kernel, dim3(1), dim3(256), 0, stream,
                       partial, maskb, out_losses);
  } else {
    float* h2f = (float*)(ws + 0);
    float* c2f = (float*)(ws + (128 << 10));
    float* bestval = (float*)(ws + (160 << 10));
    int* bestidx = (int*)(ws + (416 << 10));
    int* idx = (int*)(ws + (672 << 10));
    float* partial = (float*)(ws + (800 << 10));

    hipLaunchKernelGGL(norms_kernel, dim3(NPTS / 4), dim3(256), 0, stream, h, h2f);
    hipLaunchKernelGGL(norms_kernel, dim3(KCODES / 4), dim3(256), 0, stream, cb, c2f);
    hipLaunchKernelGGL(argmin_fp32_kernel, dim3(512), dim3(512), 0, stream,
                       h, cb, h2f, c2f, bestval, bestidx);
    hipLaunchKernelGGL(merge2_kernel, dim3(NPTS / 256), dim3(256), 0, stream,
                       bestval, bestidx, idx, out_idx_f);
    hipLaunchKernelGGL(gather_kernel, dim3(NPTS / 4), dim3(256), 0, stream,
                       h, cb, maskb, idx, zq, partial);
    hipLaunchKernelGGL(finalize_kernel, dim3(1), dim3(256), 0, stream,
                       partial, maskb, out_losses);
  }
}

// Round 9
// 848.734 us; speedup vs baseline: 3.9424x; 1.0404x over previous
//
#include <hip/hip_runtime.h>

#define NPTS   32768
#define DIM    256
#define KCODES 8192
#define TAU    2e-4f

typedef __attribute__((ext_vector_type(8))) short bf16x8;
typedef __attribute__((ext_vector_type(4))) float f32x4;

__device__ __forceinline__ unsigned short f2bf(float x) {  // RNE bf16
  unsigned u = __float_as_uint(x);
  unsigned r = (u + 0x7fffu + ((u >> 16) & 1u)) >> 16;
  return (unsigned short)r;
}
__device__ __forceinline__ float bf2f(unsigned short b) {
  return __uint_as_float(((unsigned)b) << 16);
}

// ---------------- fused hi/lo split + row squared-norms ----------------
__global__ __launch_bounds__(256) void split_norms_kernel(
    const float* __restrict__ src, unsigned short* __restrict__ hi,
    unsigned short* __restrict__ lo, float* __restrict__ norms,
    int* __restrict__ flagcnt) {
  if (flagcnt && blockIdx.x == 0 && threadIdx.x == 0) *flagcnt = 0;
  int row = blockIdx.x * 4 + (threadIdx.x >> 6);
  int lane = threadIdx.x & 63;
  float4 a = reinterpret_cast<const float4*>(src)[row * 64 + lane];
  ushort4 hq, lq;
  hq.x = f2bf(a.x); lq.x = f2bf(a.x - bf2f(hq.x));
  hq.y = f2bf(a.y); lq.y = f2bf(a.y - bf2f(hq.y));
  hq.z = f2bf(a.z); lq.z = f2bf(a.z - bf2f(hq.z));
  hq.w = f2bf(a.w); lq.w = f2bf(a.w - bf2f(hq.w));
  reinterpret_cast<ushort4*>(hi)[row * 64 + lane] = hq;
  reinterpret_cast<ushort4*>(lo)[row * 64 + lane] = lq;
  float sx = a.x * a.x, sy = a.y * a.y, sz = a.z * a.z, sw = a.w * a.w;
  double s = (double)sx + (double)sy + (double)sz + (double)sw;
#pragma unroll
  for (int m = 32; m; m >>= 1) s += __shfl_xor(s, m, 64);
  if (lane == 0) norms[row] = (float)s;
}

// standalone norms (fallback path)
__global__ __launch_bounds__(256) void norms_kernel(const float* __restrict__ src,
                                                    float* __restrict__ dst) {
  int row = blockIdx.x * 4 + (threadIdx.x >> 6);
  int lane = threadIdx.x & 63;
  float4 a = reinterpret_cast<const float4*>(src)[row * 64 + lane];
  float sx = a.x * a.x, sy = a.y * a.y, sz = a.z * a.z, sw = a.w * a.w;
  double s = (double)sx + (double)sy + (double)sz + (double)sw;
#pragma unroll
  for (int m = 32; m; m >>= 1) s += __shfl_xor(s, m, 64);
  if (lane == 0) dst[row] = (float)s;
}

// ---------------- MFMA distance GEMM + per-point top-2 (pipelined) ----------
// Geometry as r8 (8 waves 4x2, block 128pt x 128codes/cc, 3-pass bf16 split).
// New: double-buffered LDS halves + 2-deep register prefetch; ONE barrier
// per 32-k stage. Stage s: issue loads s+2 -> slot[s&1]; write slot[(s+1)&1]
// -> half[(s+1)&1]; MFMA from half[s&1]; barrier.
__global__ __launch_bounds__(512, 2) void mfma_argmin_kernel(
    const unsigned short* __restrict__ hh, const unsigned short* __restrict__ hl,
    const unsigned short* __restrict__ ch, const unsigned short* __restrict__ cl,
    const float* __restrict__ h2f, const float* __restrict__ c2f,
    float* __restrict__ bv, int* __restrict__ bi, float* __restrict__ b2o) {
  __shared__ __align__(16) unsigned short As0[2][4096], As1[2][4096],
                                           Bs0[2][4096], Bs1[2][4096];  // 64 KB
  const int t = threadIdx.x;
  const int lane = t & 63;
  const int wid = t >> 6;
  const int wrow = wid >> 1, wcol = wid & 1;
  const int b = blockIdx.x;
  const int v = (b & 7) * 64 + (b >> 3);   // XCD-chunked bijective swizzle
  const int sblk = v >> 8, pblk = v & 255;
  const int p0 = pblk * 128;
  const int cbase = sblk * (KCODES / 2);

  // staging: thread t owns one 16B block per tile per stage
  const int strow = t >> 2, stblk = t & 3;
  const int stoff = strow * 64 + ((stblk ^ ((strow >> 1) & 3)) << 4);
  const uint4* hh4 = (const uint4*)hh;
  const uint4* hl4 = (const uint4*)hl;
  const uint4* ch4 = (const uint4*)ch;
  const uint4* cl4 = (const uint4*)cl;
  const int abase4 = (p0 + strow) * 32 + stblk;     // + (s&7)*4
  const int bbase4 = (cbase + strow) * 32 + stblk;  // + (s>>3)*4096 + (s&7)*4

  // fragment read offsets
  const int ablk = lane >> 4;
  const int ar0 = wrow * 32 + (lane & 15);
  const int ar1 = ar0 + 16;
  const int aoff0 = ar0 * 64 + ((ablk ^ ((ar0 >> 1) & 3)) << 4);
  const int aoff1 = ar1 * 64 + ((ablk ^ ((ar1 >> 1) & 3)) << 4);
  int boff[4];
#pragma unroll
  for (int sc = 0; sc < 4; ++sc) {
    int cr = wcol * 64 + sc * 16 + (lane & 15);
    boff[sc] = cr * 64 + ((ablk ^ ((cr >> 1) & 3)) << 4);
  }

  float h2r[8];
#pragma unroll
  for (int sr = 0; sr < 2; ++sr)
#pragma unroll
    for (int r = 0; r < 4; ++r)
      h2r[sr * 4 + r] = h2f[p0 + wrow * 32 + sr * 16 + ((lane >> 4) << 2) + r];

  float sb1[8], sbt2[8];
  int si1[8];
#pragma unroll
  for (int q = 0; q < 8; ++q) { sb1[q] = 3.4e38f; sbt2[q] = 3.4e38f; si1[q] = 0; }

  // prologue: load stages 0,1; write stage 0 into half 0
  uint4 pa0A = hh4[abase4 + 0], pa1A = hl4[abase4 + 0];
  uint4 pb0A = ch4[bbase4 + 0], pb1A = cl4[bbase4 + 0];
  uint4 pa0B = hh4[abase4 + 4], pa1B = hl4[abase4 + 4];
  uint4 pb0B = ch4[bbase4 + 4], pb1B = cl4[bbase4 + 4];
  *(uint4*)((char*)As0[0] + stoff) = pa0A;
  *(uint4*)((char*)As1[0] + stoff) = pa1A;
  *(uint4*)((char*)Bs0[0] + stoff) = pb0A;
  *(uint4*)((char*)Bs1[0] + stoff) = pb1A;
  __syncthreads();

  f32x4 acc[8];
#pragma unroll 1
  for (int cc = 0; cc < 32; ++cc) {
#pragma unroll
    for (int dd = 0; dd < 8; ++dd) {
      const int s = cc * 8 + dd;
      if (dd == 0) {
#pragma unroll
        for (int q = 0; q < 8; ++q) acc[q] = (f32x4){0.f, 0.f, 0.f, 0.f};
      }
      // 1) issue loads for stage s+2 into slot (dd&1)
      int s2 = s + 2;
      if (s2 > 255) s2 = 255;
      const int la = abase4 + (s2 & 7) * 4;
      const int lb = bbase4 + (s2 >> 3) * 4096 + (s2 & 7) * 4;
      // 2) write stage s+1 regs into half[(dd+1)&1]
      if ((dd & 1) == 0) {
        pa0A = hh4[la]; pa1A = hl4[la]; pb0A = ch4[lb]; pb1A = cl4[lb];
        *(uint4*)((char*)As0[1] + stoff) = pa0B;
        *(uint4*)((char*)As1[1] + stoff) = pa1B;
        *(uint4*)((char*)Bs0[1] + stoff) = pb0B;
        *(uint4*)((char*)Bs1[1] + stoff) = pb1B;
      } else {
        pa0B = hh4[la]; pa1B = hl4[la]; pb0B = ch4[lb]; pb1B = cl4[lb];
        *(uint4*)((char*)As0[0] + stoff) = pa0A;
        *(uint4*)((char*)As1[0] + stoff) = pa1A;
        *(uint4*)((char*)Bs0[0] + stoff) = pb0A;
        *(uint4*)((char*)Bs1[0] + stoff) = pb1A;
      }
      // 3) MFMA from half[dd&1]
      const int hf = dd & 1;
      bf16x8 a0h = *(const bf16x8*)((const char*)As0[hf] + aoff0);
      bf16x8 a0l = *(const bf16x8*)((const char*)As1[hf] + aoff0);
      bf16x8 a1h = *(const bf16x8*)((const char*)As0[hf] + aoff1);
      bf16x8 a1l = *(const bf16x8*)((const char*)As1[hf] + aoff1);
#pragma unroll
      for (int sc = 0; sc < 4; ++sc) {
        bf16x8 bh = *(const bf16x8*)((const char*)Bs0[hf] + boff[sc]);
        bf16x8 bl = *(const bf16x8*)((const char*)Bs1[hf] + boff[sc]);
        acc[sc] = __builtin_amdgcn_mfma_f32_16x16x32_bf16(a0h, bh, acc[sc], 0, 0, 0);
        acc[sc] = __builtin_amdgcn_mfma_f32_16x16x32_bf16(a0l, bh, acc[sc], 0, 0, 0);
        acc[sc] = __builtin_amdgcn_mfma_f32_16x16x32_bf16(a0h, bl, acc[sc], 0, 0, 0);
        acc[4 + sc] = __builtin_amdgcn_mfma_f32_16x16x32_bf16(a1h, bh, acc[4 + sc], 0, 0, 0);
        acc[4 + sc] = __builtin_amdgcn_mfma_f32_16x16x32_bf16(a1l, bh, acc[4 + sc], 0, 0, 0);
        acc[4 + sc] = __builtin_amdgcn_mfma_f32_16x16x32_bf16(a1h, bl, acc[4 + sc], 0, 0, 0);
      }
      // 4) epilogue at end of cc-tile (register-only)
      if (dd == 7) {
#pragma unroll
        for (int sc = 0; sc < 4; ++sc) {
          int col = cbase + cc * 128 + wcol * 64 + sc * 16 + (lane & 15);
          float c2v = c2f[col];
#pragma unroll
          for (int sr = 0; sr < 2; ++sr)
#pragma unroll
            for (int r = 0; r < 4; ++r) {
              int slot = sr * 4 + r;
              float A = h2r[slot] + c2v;
              float sv = fmaf(-2.f, acc[sr * 4 + sc][r], A);
              if (sv < sb1[slot]) { sbt2[slot] = sb1[slot]; sb1[slot] = sv; si1[slot] = col; }
              else if (sv < sbt2[slot]) sbt2[slot] = sv;
            }
        }
      }
      __syncthreads();
    }
  }
  // cross-lane top-2 merge over the 16 col-lanes (lowest-index tiebreak on b1)
#pragma unroll
  for (int slot = 0; slot < 8; ++slot) {
    float b1 = sb1[slot]; int i1 = si1[slot]; float b2 = sbt2[slot];
#pragma unroll
    for (int m = 1; m <= 8; m <<= 1) {
      float ob1 = __shfl_xor(b1, m, 64);
      int oi1 = __shfl_xor(i1, m, 64);
      float ob2 = __shfl_xor(b2, m, 64);
      float loser = fmaxf(b1, ob1);
      float nb2 = fminf(fminf(b2, ob2), loser);
      if (ob1 < b1 || (ob1 == b1 && oi1 < i1)) { b1 = ob1; i1 = oi1; }
      b2 = nb2;
    }
    if ((lane & 15) == 0) {
      int p = p0 + wrow * 32 + (slot >> 2) * 16 + ((lane >> 4) << 2) + (slot & 3);
      int part = sblk * 2 + wcol;
      bv[part * NPTS + p] = b1;
      bi[part * NPTS + p] = i1;
      b2o[part * NPTS + p] = b2;
    }
  }
}

// ---------------- merge 4 partials + flag near-ties ----------------
__global__ __launch_bounds__(256) void merge_flag_kernel(
    const float* __restrict__ bv, const int* __restrict__ bi,
    const float* __restrict__ b2o, int* __restrict__ idx,
    float* __restrict__ out_idx_f, int* __restrict__ flagcnt,
    int* __restrict__ flaglist) {
  int p = blockIdx.x * 256 + threadIdx.x;
  float b1 = bv[p]; int i1 = bi[p]; float b2 = b2o[p];
#pragma unroll
  for (int part = 1; part < 4; ++part) {
    float pb1 = bv[part * NPTS + p];
    int pi1 = bi[part * NPTS + p];
    float pb2 = b2o[part * NPTS + p];
    float loser = fmaxf(b1, pb1);
    float nb2 = fminf(fminf(b2, pb2), loser);
    if (pb1 < b1 || (pb1 == b1 && pi1 < i1)) { b1 = pb1; i1 = pi1; }
    b2 = nb2;
  }
  idx[p] = i1;
  out_idx_f[p] = (float)i1;
  if (b2 - b1 < TAU) { int s = atomicAdd(flagcnt, 1); flaglist[s] = p; }
}

// ---------------- exact numpy-semantics re-argmin for flagged points ----------
__global__ __launch_bounds__(256) void refine_kernel(
    const float* __restrict__ h, const float* __restrict__ cb,
    const float* __restrict__ h2f, const float* __restrict__ c2f,
    const int* __restrict__ flagcnt, const int* __restrict__ flaglist,
    int* __restrict__ idx, float* __restrict__ out_idx_f) {
  __shared__ float hrow[DIM];
  __shared__ float rb[256];
  __shared__ int ri[256];
  const int n = *flagcnt;
  for (int e = blockIdx.x; e < n; e += gridDim.x) {
    const int p = flaglist[e];
    __syncthreads();
    if (threadIdx.x < DIM / 4)
      reinterpret_cast<float4*>(hrow)[threadIdx.x] =
          reinterpret_cast<const float4*>(h + p * DIM)[threadIdx.x];
    __syncthreads();
    const float h2 = h2f[p];
    float b1 = 3.4e38f;
    int i1 = 0x7fffffff;
    for (int c = threadIdx.x; c < KCODES; c += 256) {
      const float4* crow = reinterpret_cast<const float4*>(cb + c * DIM);
      float dot = 0.f;
#pragma unroll 16
      for (int d4 = 0; d4 < DIM / 4; ++d4) {
        float4 cv = crow[d4];
        dot = fmaf(hrow[4 * d4 + 0], cv.x, dot);
        dot = fmaf(hrow[4 * d4 + 1], cv.y, dot);
        dot = fmaf(hrow[4 * d4 + 2], cv.z, dot);
        dot = fmaf(hrow[4 * d4 + 3], cv.w, dot);
      }
      float A = h2 + c2f[c];
      float s = fmaf(-2.f, dot, A);
      if (s < b1) { b1 = s; i1 = c; }
    }
    rb[threadIdx.x] = b1;
    ri[threadIdx.x] = i1;
    __syncthreads();
    for (int step = 128; step; step >>= 1) {
      if (threadIdx.x < step) {
        float ob = rb[threadIdx.x + step];
        int oi = ri[threadIdx.x + step];
        if (ob < rb[threadIdx.x] || (ob == rb[threadIdx.x] && oi < ri[threadIdx.x])) {
          rb[threadIdx.x] = ob;
          ri[threadIdx.x] = oi;
        }
      }
      __syncthreads();
    }
    if (threadIdx.x == 0) { idx[p] = ri[0]; out_idx_f[p] = (float)ri[0]; }
  }
}

// ---------------- fallback: r7 fp32 argmin (8x8 tile) + 2-way merge ----------
__global__ __launch_bounds__(512, 2) void argmin_fp32_kernel(
    const float* __restrict__ h, const float* __restrict__ cb,
    const float* __restrict__ h2f, const float* __restrict__ c2f,
    float* __restrict__ bestval, int* __restrict__ bestidx) {
  __shared__ float hs[16][132];
  __shared__ float cs[16][260];
  const int t = threadIdx.x;
  const int ct = t & 31;
  const int pt = t >> 5;
  const int b = blockIdx.x;
  const int v = (b & 7) * 64 + (b >> 3);
  const int sblk = v >> 8;
  const int pblk = v & 255;
  const int p0 = pblk * 128;
  const int cbase = sblk * (KCODES / 2);
  float best[8]; int besti[8]; float h2r[8];
#pragma unroll
  for (int i = 0; i < 8; ++i) {
    best[i] = 3.4e38f; besti[i] = 0;
    h2r[i] = h2f[p0 + pt * 4 + ((i >> 2) << 6) + (i & 3)];
  }
#pragma unroll 1
  for (int cc = 0; cc < (KCODES / 2) / 256; ++cc) {
    const int c0 = cbase + cc * 256;
    float dot[8][8];
#pragma unroll
    for (int i = 0; i < 8; ++i)
#pragma unroll
      for (int j = 0; j < 8; ++j) dot[i][j] = 0.f;
#pragma unroll 1
    for (int dd = 0; dd < DIM / 16; ++dd) {
      const int d0 = dd * 16;
      {
        int p = t >> 2, k4 = (t & 3) << 2;
        float4 w = *reinterpret_cast<const float4*>(h + (p0 + p) * DIM + d0 + k4);
        hs[k4 + 0][p] = w.x; hs[k4 + 1][p] = w.y;
        hs[k4 + 2][p] = w.z; hs[k4 + 3][p] = w.w;
      }
#pragma unroll
      for (int l = 0; l < 2; ++l) {
        int F = t + l * 512;
        int c = F >> 2, k4 = (F & 3) << 2;
        float4 w = *reinterpret_cast<const float4*>(cb + (c0 + c) * DIM + d0 + k4);
        cs[k4 + 0][c] = w.x; cs[k4 + 1][c] = w.y;
        cs[k4 + 2][c] = w.z; cs[k4 + 3][c] = w.w;
      }
      __syncthreads();
#pragma unroll
      for (int k = 0; k < 16; ++k) {
        float hv[8], cv[8];
        *reinterpret_cast<float4*>(&hv[0]) = *reinterpret_cast<const float4*>(&hs[k][pt * 4]);
        *reinterpret_cast<float4*>(&hv[4]) = *reinterpret_cast<const float4*>(&hs[k][pt * 4 + 64]);
        *reinterpret_cast<float4*>(&cv[0]) = *reinterpret_cast<const float4*>(&cs[k][ct * 4]);
        *reinterpret_cast<float4*>(&cv[4]) = *reinterpret_cast<const float4*>(&cs[k][ct * 4 + 128]);
#pragma unroll
        for (int i = 0; i < 8; ++i)
#pragma unroll
          for (int j = 0; j < 8; ++j) dot[i][j] = fmaf(hv[i], cv[j], dot[i][j]);
      }
      __syncthreads();
    }
#pragma unroll
    for (int j = 0; j < 8; ++j) {
      int cl = c0 + (ct << 2) + ((j >> 2) << 7) + (j & 3);
      float cc2 = c2f[cl];
#pragma unroll
      for (int i = 0; i < 8; ++i) {
        float A = h2r[i] + cc2;
        float s = A - 2.0f * dot[i][j];
        if (s < best[i]) { best[i] = s; besti[i] = cl; }
      }
    }
  }
#pragma unroll
  for (int i = 0; i < 8; ++i) {
    float b1 = best[i]; int i1 = besti[i];
#pragma unroll
    for (int m = 16; m; m >>= 1) {
      float so = __shfl_xor(b1, m, 64);
      int io = __shfl_xor(i1, m, 64);
      if (so < b1 || (so == b1 && io < i1)) { b1 = so; i1 = io; }
    }
    if (ct == 0) {
      int p = p0 + pt * 4 + ((i >> 2) << 6) + (i & 3);
      bestval[sblk * NPTS + p] = b1;
      bestidx[sblk * NPTS + p] = i1;
    }
  }
}

__global__ __launch_bounds__(256) void merge2_kernel(
    const float* __restrict__ bestval, const int* __restrict__ bestidx,
    int* __restrict__ idx, float* __restrict__ out_idx_f) {
  int p = blockIdx.x * 256 + threadIdx.x;
  float v0 = bestval[p], v1 = bestval[NPTS + p];
  int i0 = bestidx[p], i1 = bestidx[NPTS + p];
  int w = (v1 < v0) ? i1 : i0;
  idx[p] = w;
  out_idx_f[p] = (float)w;
}

// ---------------- gather + finalize ----------------
__global__ __launch_bounds__(256) void gather_kernel(
    const float* __restrict__ h, const float* __restrict__ cb,
    const unsigned char* __restrict__ maskb, const int* __restrict__ idx,
    float* __restrict__ zq, float* __restrict__ partial) {
  int p = blockIdx.x * 4 + (threadIdx.x >> 6);
  int lane = threadIdx.x & 63;
  int ci = idx[p];
  float4 hv = reinterpret_cast<const float4*>(h)[p * (DIM / 4) + lane];
  float4 zv = reinterpret_cast<const float4*>(cb)[ci * (DIM / 4) + lane];
  float4 q;
  q.x = hv.x + (zv.x - hv.x);
  q.y = hv.y + (zv.y - hv.y);
  q.z = hv.z + (zv.z - hv.z);
  q.w = hv.w + (zv.w - hv.w);
  reinterpret_cast<float4*>(zq)[p * (DIM / 4) + lane] = q;
  float dx = hv.x - zv.x, dy = hv.y - zv.y, dz = hv.z - zv.z, dw = hv.w - zv.w;
  float s = (maskb[p] != 0) ? (dx * dx + dy * dy + dz * dz + dw * dw) : 0.f;
#pragma unroll
  for (int m = 32; m; m >>= 1) s += __shfl_xor(s, m, 64);
  __shared__ float bs[4];
  if (lane == 0) bs[threadIdx.x >> 6] = s;
  __syncthreads();
  if (threadIdx.x == 0) partial[blockIdx.x] = bs[0] + bs[1] + bs[2] + bs[3];
}

__global__ __launch_bounds__(256) void finalize_kernel(
    const float* __restrict__ partial, const unsigned char* __restrict__ maskb,
    float* __restrict__ out_losses) {
  __shared__ float red[256];
  __shared__ int redi[256];
  float s = 0.f;
  for (int i = threadIdx.x; i < NPTS / 4; i += 256) s += partial[i];
  int cnt = 0;
  for (int i = threadIdx.x; i < NPTS; i += 256) cnt += (maskb[i] != 0);
  red[threadIdx.x] = s;
  redi[threadIdx.x] = cnt;
  __syncthreads();
  for (int step = 128; step; step >>= 1) {
    if (threadIdx.x < step) {
      red[threadIdx.x] += red[threadIdx.x + step];
      redi[threadIdx.x] += redi[threadIdx.x + step];
    }
    __syncthreads();
  }
  if (threadIdx.x == 0) {
    float denom = (float)redi[0] * (float)DIM + 1e-8f;
    float loss = red[0] / denom;
    out_losses[0] = loss;
    out_losses[1] = loss;
  }
}

extern "C" void kernel_launch(void* const* d_in, const int* in_sizes, int n_in,
                              void* d_out, int out_size, void* d_ws, size_t ws_size,
                              hipStream_t stream) {
  const float* h = (const float*)d_in[0];
  const unsigned char* maskb = (const unsigned char*)d_in[1];
  const float* cb = (const float*)d_in[2];

  float* out = (float*)d_out;
  float* zq = out;
  float* out_idx_f = out + NPTS * DIM;
  float* out_losses = out + NPTS * DIM + NPTS;

  char* ws = (char*)d_ws;
  const size_t REQ = 44040192ULL;  // 42 MB

  if (ws_size >= REQ) {
    float* h2f = (float*)(ws + 0);                    // 128K
    float* c2f = (float*)(ws + 131072);               // 32K
    float* bv = (float*)(ws + 163840);                // 512K
    int* bi = (int*)(ws + 688128);                    // 512K
    float* b2o = (float*)(ws + 1212416);              // 512K
    int* idx = (int*)(ws + 1736704);                  // 128K
    float* partial = (float*)(ws + 1867776);          // 32K
    int* flagcnt = (int*)(ws + 1900544);              // 4 (+pad)
    int* flaglist = (int*)(ws + 1904640);             // 128K
    unsigned short* hh = (unsigned short*)(ws + 2097152);    // 16M
    unsigned short* hl = (unsigned short*)(ws + 18874368);   // 16M
    unsigned short* chh = (unsigned short*)(ws + 35651584);  // 4M
    unsigned short* cll = (unsigned short*)(ws + 39845888);  // 4M

    hipLaunchKernelGGL(split_norms_kernel, dim3(NPTS / 4), dim3(256), 0, stream,
                       h, hh, hl, h2f, flagcnt);
    hipLaunchKernelGGL(split_norms_kernel, dim3(KCODES / 4), dim3(256), 0, stream,
                       cb, chh, cll, c2f, flagcnt);
    hipLaunchKernelGGL(mfma_argmin_kernel, dim3(512), dim3(512), 0, stream,
                       hh, hl, chh, cll, h2f, c2f, bv, bi, b2o);
    hipLaunchKernelGGL(merge_flag_kernel, dim3(NPTS / 256), dim3(256), 0, stream,
                       bv, bi, b2o, idx, out_idx_f, flagcnt, flaglist);
    hipLaunchKernelGGL(refine_kernel, dim3(512), dim3(256), 0, stream,
                       h, cb, h2f, c2f, flagcnt, flaglist, idx, out_idx_f);
    hipLaunchKernelGGL(gather_kernel, dim3(NPTS / 4), dim3(256), 0, stream,
                       h, cb, maskb, idx, zq, partial);
    hipLaunchKernelGGL(finalize_kernel, dim3(1), dim3(256), 0, stream,
                       partial, maskb, out_losses);
  } else {
    float* h2f = (float*)(ws + 0);
    float* c2f = (float*)(ws + (128 << 10));
    float* bestval = (float*)(ws + (160 << 10));
    int* bestidx = (int*)(ws + (416 << 10));
    int* idx = (int*)(ws + (672 << 10));
    float* partial = (float*)(ws + (800 << 10));

    hipLaunchKernelGGL(norms_kernel, dim3(NPTS / 4), dim3(256), 0, stream, h, h2f);
    hipLaunchKernelGGL(norms_kernel, dim3(KCODES / 4), dim3(256), 0, stream, cb, c2f);
    hipLaunchKernelGGL(argmin_fp32_kernel, dim3(512), dim3(512), 0, stream,
                       h, cb, h2f, c2f, bestval, bestidx);
    hipLaunchKernelGGL(merge2_kernel, dim3(NPTS / 256), dim3(256), 0, stream,
                       bestval, bestidx, idx, out_idx_f);
    hipLaunchKernelGGL(gather_kernel, dim3(NPTS / 4), dim3(256), 0, stream,
                       h, cb, maskb, idx, zq, partial);
    hipLaunchKernelGGL(finalize_kernel, dim3(1), dim3(256), 0, stream,
                       partial, maskb, out_losses);
  }
}